// Round 5
// baseline (642.969 us; speedup 1.0000x reference)
//
#include <hip/hip_runtime.h>

#define N_NODES 50000
#define N_EDGES 800000
#define NFEAT   512
#define NHID    256
#define NCLASS  64

#define EDGE_BLOCKS ((N_EDGES + 255) / 256)   // 3125
#define NODE_BLOCKS ((N_NODES + 255) / 256)   // 196
#define MTILES     ((N_NODES + 63) / 64)      // 782
#define NGRP       (N_NODES / 4)              // 12500

typedef short short8  __attribute__((ext_vector_type(8)));
typedef short short2v __attribute__((ext_vector_type(2)));
typedef float floatx4 __attribute__((ext_vector_type(4)));

__device__ inline short f2bf(float f) {
    unsigned u = __builtin_bit_cast(unsigned, f);
    u += 0x7FFF + ((u >> 16) & 1);   // round-to-nearest-even
    return (short)(u >> 16);
}
__device__ inline float bf2f(short v) {
    unsigned u = ((unsigned)(unsigned short)v) << 16;
    return __builtin_bit_cast(float, u);
}

// ---------------- weight casts ----------------
__global__ __launch_bounds__(256) void cast_w1t_kernel(const float* __restrict__ W1,
                                                       short* __restrict__ Wt) {
    const int k = blockIdx.x;      // 512
    const int n = threadIdx.x;     // 256
    Wt[n * NFEAT + k] = f2bf(W1[k * NHID + n]);
}

__global__ __launch_bounds__(256) void cast_w2t_kernel(const float* __restrict__ W2,
                                                       short* __restrict__ W2t) {
    const int n = blockIdx.x;      // 64
    const int k = threadIdx.x;     // 256
    W2t[n * NHID + k] = f2bf(W2[k * NCLASS + n]);
}

// ---------------- GEMM1 (LDS-tiled MFMA, fused fp32->bf16 A-cast) --------------------
// Output h0 in SLICED layout: h0bs[(slice=col>>5)*N + row)*32 + (col&31)], bf16.
__global__ __launch_bounds__(256) void gemm1_mfma_kernel(const float* __restrict__ x,
                                                         const short* __restrict__ Wt,
                                                         short* __restrict__ h0bs) {
    __shared__ short As[64 * 32];    // 4 KB  [m][k]
    __shared__ short Bs[256 * 32];   // 16 KB [n][k]
    const int tid  = threadIdx.x;
    const int wave = tid >> 6, lane = tid & 63;
    const int mlo  = lane & 15, q = lane >> 4;
    const int m0   = blockIdx.x * 64;

    const int ar  = tid >> 2;          // staging row 0..63
    const int acg = (tid & 3) * 8;     // staging col group
    int arow = m0 + ar; if (arow >= N_NODES) arow = N_NODES - 1;   // clamp tail reads
    const float* aptr = x + (size_t)arow * NFEAT + acg;

    floatx4 acc[4][4] = {};   // [mtile][ntile]

    for (int kc = 0; kc < NFEAT; kc += 32) {
        float4 a0 = *(const float4*)(aptr + kc);
        float4 a1 = *(const float4*)(aptr + kc + 4);
        short8 ap;
        ap[0]=f2bf(a0.x); ap[1]=f2bf(a0.y); ap[2]=f2bf(a0.z); ap[3]=f2bf(a0.w);
        ap[4]=f2bf(a1.x); ap[5]=f2bf(a1.y); ap[6]=f2bf(a1.z); ap[7]=f2bf(a1.w);
        *(short8*)&As[ar * 32 + acg] = ap;
        #pragma unroll
        for (int it = 0; it < 4; ++it) {
            int g = it * 256 + tid;
            *(short8*)&Bs[g * 8] =
                *(const short8*)(Wt + (size_t)(g >> 2) * NFEAT + kc + (g & 3) * 8);
        }
        __syncthreads();

        short8 af[4], bfr[4];
        #pragma unroll
        for (int t = 0; t < 4; ++t)
            af[t] = *(const short8*)&As[(t * 16 + mlo) * 32 + q * 8];
        #pragma unroll
        for (int u = 0; u < 4; ++u)
            bfr[u] = *(const short8*)&Bs[(wave * 64 + u * 16 + mlo) * 32 + q * 8];
        #pragma unroll
        for (int t = 0; t < 4; ++t)
            #pragma unroll
            for (int u = 0; u < 4; ++u)
                acc[t][u] = __builtin_amdgcn_mfma_f32_16x16x32_bf16(af[t], bfr[u], acc[t][u], 0, 0, 0);
        __syncthreads();
    }

    #pragma unroll
    for (int t = 0; t < 4; ++t) {
        #pragma unroll
        for (int r = 0; r < 4; ++r) {
            int row = m0 + t * 16 + q * 4 + r;
            if (row < N_NODES) {
                #pragma unroll
                for (int u = 0; u < 4; ++u) {
                    int slice = wave * 2 + (u >> 1);
                    int within = (u & 1) * 16 + mlo;
                    h0bs[((size_t)slice * N_NODES + row) * 32 + within] = f2bf(acc[t][u][r]);
                }
            }
        }
    }
}

// ---------------- fused CSR build for BOTH edge lists ----------------
__global__ __launch_bounds__(256) void hist2_kernel(const int* __restrict__ ed0, int* __restrict__ deg0,
                                                    const int* __restrict__ ed1, int* __restrict__ deg1) {
    int b = blockIdx.x;
    if (b < EDGE_BLOCKS) atomicAdd(&deg0[ed0[b * 256 + threadIdx.x]], 1);
    else                 atomicAdd(&deg1[ed1[(b - EDGE_BLOCKS) * 256 + threadIdx.x]], 1);
}

__global__ __launch_bounds__(256) void scan_partial2_kernel(const int* __restrict__ deg0, int* __restrict__ p0,
                                                            const int* __restrict__ deg1, int* __restrict__ p1) {
    __shared__ int s[256];
    int which = blockIdx.x >= NODE_BLOCKS;
    int bb = blockIdx.x - which * NODE_BLOCKS;
    const int* deg = which ? deg1 : deg0;
    int* partial   = which ? p1 : p0;
    int i = bb * 256 + threadIdx.x;
    int t = threadIdx.x;
    s[t] = (i < N_NODES) ? deg[i] : 0;
    __syncthreads();
    for (int off = 128; off > 0; off >>= 1) {
        if (t < off) s[t] += s[t + off];
        __syncthreads();
    }
    if (t == 0) partial[bb] = s[0];
}

__global__ __launch_bounds__(256) void scan_top2_kernel(int* __restrict__ p0, int* __restrict__ p1) {
    __shared__ int s[256];
    int* partial = blockIdx.x ? p1 : p0;
    int t = threadIdx.x;
    int v = (t < NODE_BLOCKS) ? partial[t] : 0;
    s[t] = v;
    __syncthreads();
    for (int off = 1; off < 256; off <<= 1) {
        int a = (t >= off) ? s[t - off] : 0;
        __syncthreads();
        s[t] += a;
        __syncthreads();
    }
    if (t < NODE_BLOCKS) partial[t] = s[t] - v;   // exclusive
}

__global__ __launch_bounds__(256) void scan_final2_kernel(const int* __restrict__ deg0, const int* __restrict__ p0,
                                                          int* __restrict__ base0, int* __restrict__ cur0,
                                                          const int* __restrict__ deg1, const int* __restrict__ p1,
                                                          int* __restrict__ base1, int* __restrict__ cur1) {
    __shared__ int s[256];
    int which = blockIdx.x >= NODE_BLOCKS;
    int bb = blockIdx.x - which * NODE_BLOCKS;
    const int* deg = which ? deg1 : deg0;
    const int* partial = which ? p1 : p0;
    int* base = which ? base1 : base0;
    int* cur  = which ? cur1 : cur0;
    int i = bb * 256 + threadIdx.x;
    int t = threadIdx.x;
    int v = (i < N_NODES) ? deg[i] : 0;
    s[t] = v;
    __syncthreads();
    for (int off = 1; off < 256; off <<= 1) {
        int a = (t >= off) ? s[t - off] : 0;
        __syncthreads();
        s[t] += a;
        __syncthreads();
    }
    int excl = s[t] - v + partial[bb];
    if (i < N_NODES) { base[i] = excl; cur[i] = excl; }
}

__global__ __launch_bounds__(256) void scatter2_kernel(const int* __restrict__ es0, const int* __restrict__ ed0,
                                                       const float* __restrict__ ew0, int* __restrict__ cur0,
                                                       int2* __restrict__ edge0,
                                                       const int* __restrict__ es1, const int* __restrict__ ed1,
                                                       const float* __restrict__ ew1, int* __restrict__ cur1,
                                                       int2* __restrict__ edge1) {
    int b = blockIdx.x;
    if (b < EDGE_BLOCKS) {
        int e = b * 256 + threadIdx.x;
        int p = atomicAdd(&cur0[ed0[e]], 1);
        edge0[p] = make_int2(es0[e], __float_as_int(ew0[e]));
    } else {
        int e = (b - EDGE_BLOCKS) * 256 + threadIdx.x;
        int p = atomicAdd(&cur1[ed1[e]], 1);
        edge1[p] = make_int2(es1[e], __float_as_int(ew1[e]));
    }
}

// ---------------- SpMM1, XCD-sliced pull (8 slices x 32 features) --------------------
// slice = blockIdx & 7 -> rides the XCD round-robin so each XCD streams one 3.2MB
// slice (L2-resident). Wave per (slice,node): slot=lane>>4 walks edges stride-4,
// lane&15 covers 2 features (short2). Slots combined via shfl_xor(16,32).
__global__ __launch_bounds__(256) void spmm1_sliced_kernel(const int* __restrict__ base,
                                                           const int* __restrict__ deg,
                                                           const int2* __restrict__ edge_s,
                                                           const short* __restrict__ h0bs,
                                                           float* __restrict__ agg0s) {
    const int slice = blockIdx.x & 7;
    const int node  = (blockIdx.x >> 3) * 4 + (threadIdx.x >> 6);
    const int lane  = threadIdx.x & 63;
    const int slot  = lane >> 4;
    const int c     = lane & 15;
    const int start = base[node];
    const int len   = deg[node];
    const short* hs = h0bs + (size_t)slice * N_NODES * 32;

    float a0 = 0.f, a1 = 0.f;
    int j = slot;
    int2 e = {0, 0};
    short2v hv = {0, 0};
    if (j < len) {
        e  = edge_s[start + j];
        hv = *(const short2v*)(hs + (size_t)e.x * 32 + c * 2);
    }
    while (j < len) {
        float wt = __int_as_float(e.y);
        float v0 = bf2f(hv[0]), v1 = bf2f(hv[1]);
        int jn = j + 4;
        int2 en = e; short2v hn = hv;
        if (jn < len) {
            en = edge_s[start + jn];
            hn = *(const short2v*)(hs + (size_t)en.x * 32 + c * 2);
        }
        a0 += wt * v0; a1 += wt * v1;
        e = en; hv = hn; j = jn;
    }
    a0 += __shfl_xor(a0, 16); a0 += __shfl_xor(a0, 32);
    a1 += __shfl_xor(a1, 16); a1 += __shfl_xor(a1, 32);
    if (slot == 0) {
        float2 o = {a0, a1};
        *(float2*)(agg0s + ((size_t)slice * N_NODES + node) * 32 + c * 2) = o;
    }
}

// ---------------- GEMM2 (MFMA): h2 = relu(agg0s + b1) @ W2, sliced bf16 out ----------
__global__ __launch_bounds__(256) void gemm2_mfma_kernel(const float* __restrict__ agg0s,
                                                         const float* __restrict__ b1,
                                                         const short* __restrict__ W2t,
                                                         short* __restrict__ h2bs) {
    __shared__ short Bs[64 * 264];   // 33 KB, [n][k] pad +8
    __shared__ short As[64 * 32];    // 4 KB
    const int tid  = threadIdx.x;
    const int wave = tid >> 6, lane = tid & 63;
    const int mlo  = lane & 15, q = lane >> 4;
    const int m0   = blockIdx.x * 64;

    {   // stage full W2t [64x256] once
        int n = tid >> 2, seg = (tid & 3) * 64;
        #pragma unroll
        for (int i = 0; i < 8; ++i)
            *(short8*)&Bs[n * 264 + seg + i * 8] =
                *(const short8*)(W2t + n * NHID + seg + i * 8);
    }

    const int ar  = tid >> 2;
    const int acg = (tid & 3) * 8;
    int arow = m0 + ar; if (arow >= N_NODES) arow = N_NODES - 1;

    floatx4 acc[4] = {};   // [ntile]

    for (int kc = 0; kc < NHID; kc += 32) {
        const float* ap = agg0s + ((size_t)(kc >> 5) * N_NODES + arow) * 32 + acg;
        float4 a0 = *(const float4*)(ap);
        float4 a1 = *(const float4*)(ap + 4);
        float4 c0 = *(const float4*)(b1 + kc + acg);
        float4 c1 = *(const float4*)(b1 + kc + acg + 4);
        float v0 = a0.x + c0.x, v1 = a0.y + c0.y, v2 = a0.z + c0.z, v3 = a0.w + c0.w;
        float v4 = a1.x + c1.x, v5 = a1.y + c1.y, v6 = a1.z + c1.z, v7 = a1.w + c1.w;
        short8 apk;
        apk[0] = f2bf(v0 > 0.f ? v0 : 0.f); apk[1] = f2bf(v1 > 0.f ? v1 : 0.f);
        apk[2] = f2bf(v2 > 0.f ? v2 : 0.f); apk[3] = f2bf(v3 > 0.f ? v3 : 0.f);
        apk[4] = f2bf(v4 > 0.f ? v4 : 0.f); apk[5] = f2bf(v5 > 0.f ? v5 : 0.f);
        apk[6] = f2bf(v6 > 0.f ? v6 : 0.f); apk[7] = f2bf(v7 > 0.f ? v7 : 0.f);
        *(short8*)&As[ar * 32 + acg] = apk;
        __syncthreads();

        short8 af = *(const short8*)&As[(wave * 16 + mlo) * 32 + q * 8];
        #pragma unroll
        for (int u = 0; u < 4; ++u) {
            short8 bfr = *(const short8*)&Bs[(u * 16 + mlo) * 264 + kc + q * 8];
            acc[u] = __builtin_amdgcn_mfma_f32_16x16x32_bf16(af, bfr, acc[u], 0, 0, 0);
        }
        __syncthreads();
    }

    #pragma unroll
    for (int r = 0; r < 4; ++r) {
        int row = m0 + wave * 16 + q * 4 + r;
        if (row < N_NODES) {
            #pragma unroll
            for (int u = 0; u < 4; ++u)
                h2bs[((size_t)(u >> 1) * N_NODES + row) * 32 + (u & 1) * 16 + mlo] = f2bf(acc[u][r]);
        }
    }
}

// ---------------- SpMM2, sliced pull (2 slices x 32 features), slice-major grid ------
__global__ __launch_bounds__(256) void spmm2_sliced_kernel(const int* __restrict__ base,
                                                           const int* __restrict__ deg,
                                                           const int2* __restrict__ edge_s,
                                                           const short* __restrict__ h2bs,
                                                           float* __restrict__ agg1) {
    const int slice = (blockIdx.x >= NGRP) ? 1 : 0;
    const int grp   = blockIdx.x - slice * NGRP;
    const int node  = grp * 4 + (threadIdx.x >> 6);
    const int lane  = threadIdx.x & 63;
    const int slot  = lane >> 4;
    const int c     = lane & 15;
    const int start = base[node];
    const int len   = deg[node];
    const short* hs = h2bs + (size_t)slice * N_NODES * 32;

    float a0 = 0.f, a1 = 0.f;
    int j = slot;
    int2 e = {0, 0};
    short2v hv = {0, 0};
    if (j < len) {
        e  = edge_s[start + j];
        hv = *(const short2v*)(hs + (size_t)e.x * 32 + c * 2);
    }
    while (j < len) {
        float wt = __int_as_float(e.y);
        float v0 = bf2f(hv[0]), v1 = bf2f(hv[1]);
        int jn = j + 4;
        int2 en = e; short2v hn = hv;
        if (jn < len) {
            en = edge_s[start + jn];
            hn = *(const short2v*)(hs + (size_t)en.x * 32 + c * 2);
        }
        a0 += wt * v0; a1 += wt * v1;
        e = en; hv = hn; j = jn;
    }
    a0 += __shfl_xor(a0, 16); a0 += __shfl_xor(a0, 32);
    a1 += __shfl_xor(a1, 16); a1 += __shfl_xor(a1, 32);
    if (slot == 0) {
        float2 o = {a0, a1};
        *(float2*)(agg1 + (size_t)node * NCLASS + slice * 32 + c * 2) = o;
    }
}

// ---------------- log_softmax over 64 classes, + b2 ----------------
__global__ __launch_bounds__(256) void logsoftmax_kernel(const float* __restrict__ agg1,
                                                         const float* __restrict__ b2,
                                                         float* __restrict__ out) {
    const int lane = threadIdx.x & 63;
    const int row  = blockIdx.x * 4 + (threadIdx.x >> 6);
    float v = agg1[(size_t)row * NCLASS + lane] + b2[lane];

    float m = v;
    #pragma unroll
    for (int off = 32; off > 0; off >>= 1) m = fmaxf(m, __shfl_xor(m, off, 64));
    float ex = expf(v - m);
    float s = ex;
    #pragma unroll
    for (int off = 32; off > 0; off >>= 1) s += __shfl_xor(s, off, 64);

    out[(size_t)row * NCLASS + lane] = v - m - logf(s);
}

extern "C" void kernel_launch(void* const* d_in, const int* in_sizes, int n_in,
                              void* d_out, int out_size, void* d_ws, size_t ws_size,
                              hipStream_t stream) {
    const float* x   = (const float*)d_in[0];
    const int*   es0 = (const int*)  d_in[1];
    const int*   ed0 = (const int*)  d_in[2];
    const float* ew0 = (const float*)d_in[3];
    const int*   es1 = (const int*)  d_in[4];
    const int*   ed1 = (const int*)  d_in[5];
    const float* ew1 = (const float*)d_in[6];
    const float* W1  = (const float*)d_in[7];
    const float* b1  = (const float*)d_in[8];
    const float* W2  = (const float*)d_in[9];
    const float* b2  = (const float*)d_in[10];
    float* out = (float*)d_out;

    // ws layout (102.4 MB):
    //   [0, 25.6MB):    h0bs bf16 sliced [8][50000][32]; later h2bs [2][50000][32] bf16
    //                   at [0,6.4) + agg1 fp32 [6.4,19.2)
    //   [25.6,32.6MB):  CSR1 (deg1/base1/cursor1/partial1/edge_s1)
    //   [51.2,102.4):   agg0s fp32 sliced [8][50000][32]
    char* ws = (char*)d_ws;
    const size_t SZ_H0 = (size_t)N_NODES * NHID * sizeof(short);   // 25.6 MB
    short* h0bs  = (short*)ws;
    short* h2bs  = (short*)ws;
    float* agg1  = (float*)(ws + (size_t)N_NODES * NCLASS * sizeof(short));  // 6.4MB
    float* agg0s = (float*)(ws + (size_t)N_NODES * NHID * sizeof(float));    // 51.2MB

    char* c1 = ws + SZ_H0;
    int*   deg1     = (int*)c1;
    int*   base1    = deg1 + N_NODES;
    int*   cursor1  = base1 + N_NODES;
    int*   partial1 = cursor1 + N_NODES;
    int2*  edge1    = (int2*)(partial1 + 1024);

    // d_out scratch (12.8 MB; fully overwritten by logsoftmax):
    //   [0, 7.0MB): CSR0;  [8MiB,+0.5MiB): Wt;  [9MiB,+32KB): W2t
    int*   deg0     = (int*)d_out;
    int*   base0    = deg0 + N_NODES;
    int*   cursor0  = base0 + N_NODES;
    int*   partial0 = cursor0 + N_NODES;
    int2*  edge0    = (int2*)(partial0 + 1024);
    short* Wt       = (short*)((char*)d_out + (8u << 20));
    short* W2t      = (short*)((char*)d_out + (9u << 20));

    // ---- build both CSRs up-front (fused) ----
    hipMemsetAsync(deg0, 0, N_NODES * sizeof(int), stream);
    hipMemsetAsync(deg1, 0, N_NODES * sizeof(int), stream);
    hist2_kernel<<<2 * EDGE_BLOCKS, 256, 0, stream>>>(ed0, deg0, ed1, deg1);
    scan_partial2_kernel<<<2 * NODE_BLOCKS, 256, 0, stream>>>(deg0, partial0, deg1, partial1);
    scan_top2_kernel<<<2, 256, 0, stream>>>(partial0, partial1);
    scan_final2_kernel<<<2 * NODE_BLOCKS, 256, 0, stream>>>(deg0, partial0, base0, cursor0,
                                                            deg1, partial1, base1, cursor1);
    scatter2_kernel<<<2 * EDGE_BLOCKS, 256, 0, stream>>>(es0, ed0, ew0, cursor0, edge0,
                                                         es1, ed1, ew1, cursor1, edge1);

    // ---- weights ----
    cast_w1t_kernel<<<NFEAT, 256, 0, stream>>>(W1, Wt);
    cast_w2t_kernel<<<NCLASS, 256, 0, stream>>>(W2, W2t);

    // ---- layer 1 ----
    gemm1_mfma_kernel<<<MTILES, 256, 0, stream>>>(x, Wt, h0bs);
    spmm1_sliced_kernel<<<NGRP * 8, 256, 0, stream>>>(base0, deg0, edge0, h0bs, agg0s);

    // ---- layer 2 ----
    gemm2_mfma_kernel<<<MTILES, 256, 0, stream>>>(agg0s, b1, W2t, h2bs);
    spmm2_sliced_kernel<<<NGRP * 2, 256, 0, stream>>>(base1, deg1, edge1, h2bs, agg1);
    logsoftmax_kernel<<<N_NODES / 4, 256, 0, stream>>>(agg1, b2, out);
}

// Round 6
// 498.352 us; speedup vs baseline: 1.2902x; 1.2902x over previous
//
#include <hip/hip_runtime.h>

#define N_NODES 50000
#define N_EDGES 800000
#define NFEAT   512
#define NHID    256
#define NCLASS  64

#define EDGE_BLOCKS ((N_EDGES + 255) / 256)   // 3125
#define NODE_BLOCKS ((N_NODES + 255) / 256)   // 196
#define MTILES     ((N_NODES + 63) / 64)      // 782

typedef short short8  __attribute__((ext_vector_type(8)));
typedef float floatx4 __attribute__((ext_vector_type(4)));

__device__ inline short f2bf(float f) {
    unsigned u = __builtin_bit_cast(unsigned, f);
    u += 0x7FFF + ((u >> 16) & 1);   // round-to-nearest-even
    return (short)(u >> 16);
}
__device__ inline float bf2f(short v) {
    unsigned u = ((unsigned)(unsigned short)v) << 16;
    return __builtin_bit_cast(float, u);
}

// ---------------- weight casts ----------------
__global__ __launch_bounds__(256) void cast_w1t_kernel(const float* __restrict__ W1,
                                                       short* __restrict__ Wt) {
    const int k = blockIdx.x;      // 512
    const int n = threadIdx.x;     // 256
    Wt[n * NFEAT + k] = f2bf(W1[k * NHID + n]);
}

__global__ __launch_bounds__(256) void cast_w2t_kernel(const float* __restrict__ W2,
                                                       short* __restrict__ W2t) {
    const int n = blockIdx.x;      // 64
    const int k = threadIdx.x;     // 256
    W2t[n * NHID + k] = f2bf(W2[k * NCLASS + n]);
}

// ---------------- GEMM1 (LDS-tiled MFMA, fused fp32->bf16 A-cast), h0 bf16 row-major -
__global__ __launch_bounds__(256) void gemm1_mfma_kernel(const float* __restrict__ x,
                                                         const short* __restrict__ Wt,
                                                         short* __restrict__ h0b) {
    __shared__ short As[64 * 32];    // 4 KB  [m][k]
    __shared__ short Bs[256 * 32];   // 16 KB [n][k]
    const int tid  = threadIdx.x;
    const int wave = tid >> 6, lane = tid & 63;
    const int mlo  = lane & 15, q = lane >> 4;
    const int m0   = blockIdx.x * 64;

    const int ar  = tid >> 2;          // staging row 0..63
    const int acg = (tid & 3) * 8;     // staging col group
    int arow = m0 + ar; if (arow >= N_NODES) arow = N_NODES - 1;   // clamp tail reads
    const float* aptr = x + (size_t)arow * NFEAT + acg;

    floatx4 acc[4][4] = {};   // [mtile][ntile]

    for (int kc = 0; kc < NFEAT; kc += 32) {
        float4 a0 = *(const float4*)(aptr + kc);
        float4 a1 = *(const float4*)(aptr + kc + 4);
        short8 ap;
        ap[0]=f2bf(a0.x); ap[1]=f2bf(a0.y); ap[2]=f2bf(a0.z); ap[3]=f2bf(a0.w);
        ap[4]=f2bf(a1.x); ap[5]=f2bf(a1.y); ap[6]=f2bf(a1.z); ap[7]=f2bf(a1.w);
        *(short8*)&As[ar * 32 + acg] = ap;
        #pragma unroll
        for (int it = 0; it < 4; ++it) {
            int g = it * 256 + tid;
            *(short8*)&Bs[g * 8] =
                *(const short8*)(Wt + (size_t)(g >> 2) * NFEAT + kc + (g & 3) * 8);
        }
        __syncthreads();

        short8 af[4], bfr[4];
        #pragma unroll
        for (int t = 0; t < 4; ++t)
            af[t] = *(const short8*)&As[(t * 16 + mlo) * 32 + q * 8];
        #pragma unroll
        for (int u = 0; u < 4; ++u)
            bfr[u] = *(const short8*)&Bs[(wave * 64 + u * 16 + mlo) * 32 + q * 8];
        #pragma unroll
        for (int t = 0; t < 4; ++t)
            #pragma unroll
            for (int u = 0; u < 4; ++u)
                acc[t][u] = __builtin_amdgcn_mfma_f32_16x16x32_bf16(af[t], bfr[u], acc[t][u], 0, 0, 0);
        __syncthreads();
    }

    #pragma unroll
    for (int t = 0; t < 4; ++t) {
        #pragma unroll
        for (int r = 0; r < 4; ++r) {
            int row = m0 + t * 16 + q * 4 + r;
            if (row < N_NODES) {
                #pragma unroll
                for (int u = 0; u < 4; ++u)
                    h0b[(size_t)row * NHID + wave * 64 + u * 16 + mlo] = f2bf(acc[t][u][r]);
            }
        }
    }
}

// ---------------- fused CSR build for BOTH edge lists ----------------
__global__ __launch_bounds__(256) void hist2_kernel(const int* __restrict__ ed0, int* __restrict__ deg0,
                                                    const int* __restrict__ ed1, int* __restrict__ deg1) {
    int b = blockIdx.x;
    if (b < EDGE_BLOCKS) atomicAdd(&deg0[ed0[b * 256 + threadIdx.x]], 1);
    else                 atomicAdd(&deg1[ed1[(b - EDGE_BLOCKS) * 256 + threadIdx.x]], 1);
}

__global__ __launch_bounds__(256) void scan_partial2_kernel(const int* __restrict__ deg0, int* __restrict__ p0,
                                                            const int* __restrict__ deg1, int* __restrict__ p1) {
    __shared__ int s[256];
    int which = blockIdx.x >= NODE_BLOCKS;
    int bb = blockIdx.x - which * NODE_BLOCKS;
    const int* deg = which ? deg1 : deg0;
    int* partial   = which ? p1 : p0;
    int i = bb * 256 + threadIdx.x;
    int t = threadIdx.x;
    s[t] = (i < N_NODES) ? deg[i] : 0;
    __syncthreads();
    for (int off = 128; off > 0; off >>= 1) {
        if (t < off) s[t] += s[t + off];
        __syncthreads();
    }
    if (t == 0) partial[bb] = s[0];
}

__global__ __launch_bounds__(256) void scan_top2_kernel(int* __restrict__ p0, int* __restrict__ p1) {
    __shared__ int s[256];
    int* partial = blockIdx.x ? p1 : p0;
    int t = threadIdx.x;
    int v = (t < NODE_BLOCKS) ? partial[t] : 0;
    s[t] = v;
    __syncthreads();
    for (int off = 1; off < 256; off <<= 1) {
        int a = (t >= off) ? s[t - off] : 0;
        __syncthreads();
        s[t] += a;
        __syncthreads();
    }
    if (t < NODE_BLOCKS) partial[t] = s[t] - v;   // exclusive
}

__global__ __launch_bounds__(256) void scan_final2_kernel(const int* __restrict__ deg0, const int* __restrict__ p0,
                                                          int* __restrict__ base0, int* __restrict__ cur0,
                                                          const int* __restrict__ deg1, const int* __restrict__ p1,
                                                          int* __restrict__ base1, int* __restrict__ cur1) {
    __shared__ int s[256];
    int which = blockIdx.x >= NODE_BLOCKS;
    int bb = blockIdx.x - which * NODE_BLOCKS;
    const int* deg = which ? deg1 : deg0;
    const int* partial = which ? p1 : p0;
    int* base = which ? base1 : base0;
    int* cur  = which ? cur1 : cur0;
    int i = bb * 256 + threadIdx.x;
    int t = threadIdx.x;
    int v = (i < N_NODES) ? deg[i] : 0;
    s[t] = v;
    __syncthreads();
    for (int off = 1; off < 256; off <<= 1) {
        int a = (t >= off) ? s[t - off] : 0;
        __syncthreads();
        s[t] += a;
        __syncthreads();
    }
    int excl = s[t] - v + partial[bb];
    if (i < N_NODES) { base[i] = excl; cur[i] = excl; }
}

__global__ __launch_bounds__(256) void scatter2_kernel(const int* __restrict__ es0, const int* __restrict__ ed0,
                                                       const float* __restrict__ ew0, int* __restrict__ cur0,
                                                       int2* __restrict__ edge0,
                                                       const int* __restrict__ es1, const int* __restrict__ ed1,
                                                       const float* __restrict__ ew1, int* __restrict__ cur1,
                                                       int2* __restrict__ edge1) {
    int b = blockIdx.x;
    if (b < EDGE_BLOCKS) {
        int e = b * 256 + threadIdx.x;
        int p = atomicAdd(&cur0[ed0[e]], 1);
        edge0[p] = make_int2(es0[e], __float_as_int(ew0[e]));
    } else {
        int e = (b - EDGE_BLOCKS) * 256 + threadIdx.x;
        int p = atomicAdd(&cur1[ed1[e]], 1);
        edge1[p] = make_int2(es1[e], __float_as_int(ew1[e]));
    }
}

// ---------------- SpMM1 pull (bf16, d=256): wave per node, 2 edge slots --------------
// slot=lane>>5 walks edges stride-2; 32 lanes x short8 (16B) cover the 512B row.
// Slots combined by shfl_xor(32). 1-ahead prefetch per slot.
__global__ __launch_bounds__(256) void spmm1_pull_kernel(const int* __restrict__ base,
                                                         const int* __restrict__ deg,
                                                         const int2* __restrict__ edge_s,
                                                         const short* __restrict__ h0b,
                                                         float* __restrict__ agg0) {
    const int node = blockIdx.x * 4 + (threadIdx.x >> 6);
    const int lane = threadIdx.x & 63;
    const int slot = lane >> 5;
    const int c    = lane & 31;         // feature group: feats c*8..c*8+7
    const int start = base[node];
    const int len   = deg[node];

    float acc[8] = {0.f,0.f,0.f,0.f,0.f,0.f,0.f,0.f};
    int j = slot;
    int2 e = {0, 0};
    short8 hv = {0,0,0,0,0,0,0,0};
    if (j < len) {
        e  = edge_s[start + j];
        hv = *(const short8*)(h0b + (size_t)e.x * NHID + c * 8);
    }
    while (j < len) {
        float wt = __int_as_float(e.y);
        int jn = j + 2;
        int2 en = e; short8 hn = hv;
        if (jn < len) {
            en = edge_s[start + jn];
            hn = *(const short8*)(h0b + (size_t)en.x * NHID + c * 8);
        }
        #pragma unroll
        for (int k = 0; k < 8; ++k) acc[k] += wt * bf2f(hv[k]);
        e = en; hv = hn; j = jn;
    }
    #pragma unroll
    for (int k = 0; k < 8; ++k) acc[k] += __shfl_xor(acc[k], 32);
    if (slot == 0) {
        float4 o0 = {acc[0], acc[1], acc[2], acc[3]};
        float4 o1 = {acc[4], acc[5], acc[6], acc[7]};
        float* p = agg0 + (size_t)node * NHID + c * 8;
        *(float4*)p = o0;
        *(float4*)(p + 4) = o1;
    }
}

// ---------------- GEMM2 (MFMA): h2 = relu(agg0 + b1) @ W2, bf16 row-major out --------
__global__ __launch_bounds__(256) void gemm2_mfma_kernel(const float* __restrict__ agg0,
                                                         const float* __restrict__ b1,
                                                         const short* __restrict__ W2t,
                                                         short* __restrict__ h2b) {
    __shared__ short Bs[64 * 264];   // 33 KB, [n][k] pad +8
    __shared__ short As[64 * 32];    // 4 KB
    const int tid  = threadIdx.x;
    const int wave = tid >> 6, lane = tid & 63;
    const int mlo  = lane & 15, q = lane >> 4;
    const int m0   = blockIdx.x * 64;

    {   // stage full W2t [64x256] once
        int n = tid >> 2, seg = (tid & 3) * 64;
        #pragma unroll
        for (int i = 0; i < 8; ++i)
            *(short8*)&Bs[n * 264 + seg + i * 8] =
                *(const short8*)(W2t + n * NHID + seg + i * 8);
    }

    const int ar  = tid >> 2;
    const int acg = (tid & 3) * 8;
    int arow = m0 + ar; if (arow >= N_NODES) arow = N_NODES - 1;
    const float* aptr = agg0 + (size_t)arow * NHID + acg;

    floatx4 acc[4] = {};   // [ntile]

    for (int kc = 0; kc < NHID; kc += 32) {
        float4 a0 = *(const float4*)(aptr + kc);
        float4 a1 = *(const float4*)(aptr + kc + 4);
        float4 c0 = *(const float4*)(b1 + kc + acg);
        float4 c1 = *(const float4*)(b1 + kc + acg + 4);
        float v0 = a0.x + c0.x, v1 = a0.y + c0.y, v2 = a0.z + c0.z, v3 = a0.w + c0.w;
        float v4 = a1.x + c1.x, v5 = a1.y + c1.y, v6 = a1.z + c1.z, v7 = a1.w + c1.w;
        short8 apk;
        apk[0] = f2bf(v0 > 0.f ? v0 : 0.f); apk[1] = f2bf(v1 > 0.f ? v1 : 0.f);
        apk[2] = f2bf(v2 > 0.f ? v2 : 0.f); apk[3] = f2bf(v3 > 0.f ? v3 : 0.f);
        apk[4] = f2bf(v4 > 0.f ? v4 : 0.f); apk[5] = f2bf(v5 > 0.f ? v5 : 0.f);
        apk[6] = f2bf(v6 > 0.f ? v6 : 0.f); apk[7] = f2bf(v7 > 0.f ? v7 : 0.f);
        *(short8*)&As[ar * 32 + acg] = apk;
        __syncthreads();

        short8 af = *(const short8*)&As[(wave * 16 + mlo) * 32 + q * 8];
        #pragma unroll
        for (int u = 0; u < 4; ++u) {
            short8 bfr = *(const short8*)&Bs[(u * 16 + mlo) * 264 + kc + q * 8];
            acc[u] = __builtin_amdgcn_mfma_f32_16x16x32_bf16(af, bfr, acc[u], 0, 0, 0);
        }
        __syncthreads();
    }

    #pragma unroll
    for (int r = 0; r < 4; ++r) {
        int row = m0 + wave * 16 + q * 4 + r;
        if (row < N_NODES) {
            #pragma unroll
            for (int u = 0; u < 4; ++u)
                h2b[(size_t)row * NCLASS + u * 16 + mlo] = f2bf(acc[u][r]);
        }
    }
}

// ---------------- Fused SpMM2 + bias + log_softmax (d=64) ----------------
// Wave per node. slot=lane>>3 (8 slots, 8 edges in flight); f=lane&7 covers feats
// f*8..f*8+7 via short8 (16B). Butterfly slot-reduce => every lane holds its f-group's
// aggregated values; then in-register bias + log_softmax; slot 0 stores.
__global__ __launch_bounds__(256) void spmm2_lsm_kernel(const int* __restrict__ base,
                                                        const int* __restrict__ deg,
                                                        const int2* __restrict__ edge_s,
                                                        const short* __restrict__ h2b,
                                                        const float* __restrict__ b2,
                                                        float* __restrict__ out) {
    const int node = blockIdx.x * 4 + (threadIdx.x >> 6);
    const int lane = threadIdx.x & 63;
    const int slot = lane >> 3;
    const int f    = lane & 7;          // feats f*8..f*8+7
    const int start = base[node];
    const int len   = deg[node];

    float acc[8] = {0.f,0.f,0.f,0.f,0.f,0.f,0.f,0.f};
    int j = slot;
    int2 e = {0, 0};
    short8 hv = {0,0,0,0,0,0,0,0};
    if (j < len) {
        e  = edge_s[start + j];
        hv = *(const short8*)(h2b + (size_t)e.x * NCLASS + f * 8);
    }
    while (j < len) {
        float wt = __int_as_float(e.y);
        int jn = j + 8;
        int2 en = e; short8 hn = hv;
        if (jn < len) {
            en = edge_s[start + jn];
            hn = *(const short8*)(h2b + (size_t)en.x * NCLASS + f * 8);
        }
        #pragma unroll
        for (int k = 0; k < 8; ++k) acc[k] += wt * bf2f(hv[k]);
        e = en; hv = hn; j = jn;
    }
    // butterfly across slots (lane bits 3,4,5) -> allreduce within f-group
    #pragma unroll
    for (int k = 0; k < 8; ++k) {
        acc[k] += __shfl_xor(acc[k], 8);
        acc[k] += __shfl_xor(acc[k], 16);
        acc[k] += __shfl_xor(acc[k], 32);
    }
    // + bias
    float4 c0 = *(const float4*)(b2 + f * 8);
    float4 c1 = *(const float4*)(b2 + f * 8 + 4);
    float v[8];
    v[0] = acc[0] + c0.x; v[1] = acc[1] + c0.y; v[2] = acc[2] + c0.z; v[3] = acc[3] + c0.w;
    v[4] = acc[4] + c1.x; v[5] = acc[5] + c1.y; v[6] = acc[6] + c1.z; v[7] = acc[7] + c1.w;
    // log_softmax across 64 classes: local 8 + butterfly over f bits (1,2,4)
    float m = v[0];
    #pragma unroll
    for (int k = 1; k < 8; ++k) m = fmaxf(m, v[k]);
    m = fmaxf(m, __shfl_xor(m, 1));
    m = fmaxf(m, __shfl_xor(m, 2));
    m = fmaxf(m, __shfl_xor(m, 4));
    float s = 0.f;
    #pragma unroll
    for (int k = 0; k < 8; ++k) s += __expf(v[k] - m);
    s += __shfl_xor(s, 1);
    s += __shfl_xor(s, 2);
    s += __shfl_xor(s, 4);
    float ls = m + __logf(s);
    if (slot == 0) {
        float4 o0 = {v[0] - ls, v[1] - ls, v[2] - ls, v[3] - ls};
        float4 o1 = {v[4] - ls, v[5] - ls, v[6] - ls, v[7] - ls};
        float* p = out + (size_t)node * NCLASS + f * 8;
        *(float4*)p = o0;
        *(float4*)(p + 4) = o1;
    }
}

extern "C" void kernel_launch(void* const* d_in, const int* in_sizes, int n_in,
                              void* d_out, int out_size, void* d_ws, size_t ws_size,
                              hipStream_t stream) {
    const float* x   = (const float*)d_in[0];
    const int*   es0 = (const int*)  d_in[1];
    const int*   ed0 = (const int*)  d_in[2];
    const float* ew0 = (const float*)d_in[3];
    const int*   es1 = (const int*)  d_in[4];
    const int*   ed1 = (const int*)  d_in[5];
    const float* ew1 = (const float*)d_in[6];
    const float* W1  = (const float*)d_in[7];
    const float* b1  = (const float*)d_in[8];
    const float* W2  = (const float*)d_in[9];
    const float* b2  = (const float*)d_in[10];
    float* out = (float*)d_out;

    // ws layout (102.4 MB):
    //   [0, 25.6MB):   h0b bf16 [50000x256]; later h2b bf16 [50000x64] at [0,6.4)
    //   [25.6,32.6MB): CSR1 (deg1/base1/cursor1/partial1/edge1) — lives until spmm2
    //   [51.2,102.4):  agg0 fp32 [50000x256]
    char* ws = (char*)d_ws;
    const size_t SZ_H0 = (size_t)N_NODES * NHID * sizeof(short);   // 25.6 MB
    short* h0b  = (short*)ws;
    short* h2b  = (short*)ws;
    float* agg0 = (float*)(ws + (size_t)N_NODES * NHID * sizeof(float));   // 51.2MB

    char* c1 = ws + SZ_H0;
    int*   deg1     = (int*)c1;
    int*   base1    = deg1 + N_NODES;
    int*   cursor1  = base1 + N_NODES;
    int*   partial1 = cursor1 + N_NODES;
    int2*  edge1    = (int2*)(partial1 + 1024);

    // d_out scratch (12.8 MB; CSR0 dead after spmm1; Wt/W2t dead after gemms;
    // final fused spmm2+logsoftmax overwrites all of d_out):
    int*   deg0     = (int*)d_out;
    int*   base0    = deg0 + N_NODES;
    int*   cursor0  = base0 + N_NODES;
    int*   partial0 = cursor0 + N_NODES;
    int2*  edge0    = (int2*)(partial0 + 1024);
    short* Wt       = (short*)((char*)d_out + (8u << 20));
    short* W2t      = (short*)((char*)d_out + (9u << 20));

    // ---- build both CSRs up-front (fused) ----
    hipMemsetAsync(deg0, 0, N_NODES * sizeof(int), stream);
    hipMemsetAsync(deg1, 0, N_NODES * sizeof(int), stream);
    hist2_kernel<<<2 * EDGE_BLOCKS, 256, 0, stream>>>(ed0, deg0, ed1, deg1);
    scan_partial2_kernel<<<2 * NODE_BLOCKS, 256, 0, stream>>>(deg0, partial0, deg1, partial1);
    scan_top2_kernel<<<2, 256, 0, stream>>>(partial0, partial1);
    scan_final2_kernel<<<2 * NODE_BLOCKS, 256, 0, stream>>>(deg0, partial0, base0, cursor0,
                                                            deg1, partial1, base1, cursor1);
    scatter2_kernel<<<2 * EDGE_BLOCKS, 256, 0, stream>>>(es0, ed0, ew0, cursor0, edge0,
                                                         es1, ed1, ew1, cursor1, edge1);

    // ---- weights ----
    cast_w1t_kernel<<<NFEAT, 256, 0, stream>>>(W1, Wt);
    cast_w2t_kernel<<<NCLASS, 256, 0, stream>>>(W2, W2t);

    // ---- layer 1 ----
    gemm1_mfma_kernel<<<MTILES, 256, 0, stream>>>(x, Wt, h0b);
    spmm1_pull_kernel<<<N_NODES / 4, 256, 0, stream>>>(base0, deg0, edge0, h0b, agg0);

    // ---- layer 2 (spmm2 fused with bias + log_softmax, writes out directly) ----
    gemm2_mfma_kernel<<<MTILES, 256, 0, stream>>>(agg0, b1, W2t, h2b);
    spmm2_lsm_kernel<<<N_NODES / 4, 256, 0, stream>>>(base1, deg1, edge1, h2b, b2, out);
}

// Round 7
// 490.167 us; speedup vs baseline: 1.3117x; 1.0167x over previous
//
#include <hip/hip_runtime.h>

#define N_NODES 50000
#define N_EDGES 800000
#define NFEAT   512
#define NHID    256
#define NCLASS  64

#define EDGE_BLOCKS ((N_EDGES + 255) / 256)   // 3125
#define NODE_BLOCKS ((N_NODES + 255) / 256)   // 196
#define MTILES     ((N_NODES + 63) / 64)      // 782

typedef short short8  __attribute__((ext_vector_type(8)));
typedef float floatx4 __attribute__((ext_vector_type(4)));

__device__ inline short f2bf(float f) {
    unsigned u = __builtin_bit_cast(unsigned, f);
    u += 0x7FFF + ((u >> 16) & 1);   // round-to-nearest-even
    return (short)(u >> 16);
}
__device__ inline float bf2f(short v) {
    unsigned u = ((unsigned)(unsigned short)v) << 16;
    return __builtin_bit_cast(float, u);
}
// packed edge: low 16 bits = src node id (50000 < 65536), high 16 = bf16 weight
__device__ inline int pack_edge(int src, float w) {
    return (src & 0xFFFF) | ((int)(unsigned short)f2bf(w) << 16);
}

// ---------------- weight casts ----------------
__global__ __launch_bounds__(256) void cast_w1t_kernel(const float* __restrict__ W1,
                                                       short* __restrict__ Wt) {
    const int k = blockIdx.x;      // 512
    const int n = threadIdx.x;     // 256
    Wt[n * NFEAT + k] = f2bf(W1[k * NHID + n]);
}

__global__ __launch_bounds__(256) void cast_w2t_kernel(const float* __restrict__ W2,
                                                       short* __restrict__ W2t) {
    const int n = blockIdx.x;      // 64
    const int k = threadIdx.x;     // 256
    W2t[n * NHID + k] = f2bf(W2[k * NCLASS + n]);
}

// ---------------- GEMM1 (LDS-tiled MFMA, fused fp32->bf16 A-cast), h0 bf16 row-major -
__global__ __launch_bounds__(256) void gemm1_mfma_kernel(const float* __restrict__ x,
                                                         const short* __restrict__ Wt,
                                                         short* __restrict__ h0b) {
    __shared__ short As[64 * 32];    // 4 KB  [m][k]
    __shared__ short Bs[256 * 32];   // 16 KB [n][k]
    const int tid  = threadIdx.x;
    const int wave = tid >> 6, lane = tid & 63;
    const int mlo  = lane & 15, q = lane >> 4;
    const int m0   = blockIdx.x * 64;

    const int ar  = tid >> 2;          // staging row 0..63
    const int acg = (tid & 3) * 8;     // staging col group
    int arow = m0 + ar; if (arow >= N_NODES) arow = N_NODES - 1;   // clamp tail reads
    const float* aptr = x + (size_t)arow * NFEAT + acg;

    floatx4 acc[4][4] = {};   // [mtile][ntile]

    for (int kc = 0; kc < NFEAT; kc += 32) {
        float4 a0 = *(const float4*)(aptr + kc);
        float4 a1 = *(const float4*)(aptr + kc + 4);
        short8 ap;
        ap[0]=f2bf(a0.x); ap[1]=f2bf(a0.y); ap[2]=f2bf(a0.z); ap[3]=f2bf(a0.w);
        ap[4]=f2bf(a1.x); ap[5]=f2bf(a1.y); ap[6]=f2bf(a1.z); ap[7]=f2bf(a1.w);
        *(short8*)&As[ar * 32 + acg] = ap;
        #pragma unroll
        for (int it = 0; it < 4; ++it) {
            int g = it * 256 + tid;
            *(short8*)&Bs[g * 8] =
                *(const short8*)(Wt + (size_t)(g >> 2) * NFEAT + kc + (g & 3) * 8);
        }
        __syncthreads();

        short8 af[4], bfr[4];
        #pragma unroll
        for (int t = 0; t < 4; ++t)
            af[t] = *(const short8*)&As[(t * 16 + mlo) * 32 + q * 8];
        #pragma unroll
        for (int u = 0; u < 4; ++u)
            bfr[u] = *(const short8*)&Bs[(wave * 64 + u * 16 + mlo) * 32 + q * 8];
        #pragma unroll
        for (int t = 0; t < 4; ++t)
            #pragma unroll
            for (int u = 0; u < 4; ++u)
                acc[t][u] = __builtin_amdgcn_mfma_f32_16x16x32_bf16(af[t], bfr[u], acc[t][u], 0, 0, 0);
        __syncthreads();
    }

    #pragma unroll
    for (int t = 0; t < 4; ++t) {
        #pragma unroll
        for (int r = 0; r < 4; ++r) {
            int row = m0 + t * 16 + q * 4 + r;
            if (row < N_NODES) {
                #pragma unroll
                for (int u = 0; u < 4; ++u)
                    h0b[(size_t)row * NHID + wave * 64 + u * 16 + mlo] = f2bf(acc[t][u][r]);
            }
        }
    }
}

// ---------------- fused CSR build for BOTH edge lists ----------------
__global__ __launch_bounds__(256) void hist2_kernel(const int* __restrict__ ed0, int* __restrict__ deg0,
                                                    const int* __restrict__ ed1, int* __restrict__ deg1) {
    int b = blockIdx.x;
    if (b < EDGE_BLOCKS) atomicAdd(&deg0[ed0[b * 256 + threadIdx.x]], 1);
    else                 atomicAdd(&deg1[ed1[(b - EDGE_BLOCKS) * 256 + threadIdx.x]], 1);
}

__global__ __launch_bounds__(256) void scan_partial2_kernel(const int* __restrict__ deg0, int* __restrict__ p0,
                                                            const int* __restrict__ deg1, int* __restrict__ p1) {
    __shared__ int s[256];
    int which = blockIdx.x >= NODE_BLOCKS;
    int bb = blockIdx.x - which * NODE_BLOCKS;
    const int* deg = which ? deg1 : deg0;
    int* partial   = which ? p1 : p0;
    int i = bb * 256 + threadIdx.x;
    int t = threadIdx.x;
    s[t] = (i < N_NODES) ? deg[i] : 0;
    __syncthreads();
    for (int off = 128; off > 0; off >>= 1) {
        if (t < off) s[t] += s[t + off];
        __syncthreads();
    }
    if (t == 0) partial[bb] = s[0];
}

__global__ __launch_bounds__(256) void scan_top2_kernel(int* __restrict__ p0, int* __restrict__ p1) {
    __shared__ int s[256];
    int* partial = blockIdx.x ? p1 : p0;
    int t = threadIdx.x;
    int v = (t < NODE_BLOCKS) ? partial[t] : 0;
    s[t] = v;
    __syncthreads();
    for (int off = 1; off < 256; off <<= 1) {
        int a = (t >= off) ? s[t - off] : 0;
        __syncthreads();
        s[t] += a;
        __syncthreads();
    }
    if (t < NODE_BLOCKS) partial[t] = s[t] - v;   // exclusive
}

__global__ __launch_bounds__(256) void scan_final2_kernel(const int* __restrict__ deg0, const int* __restrict__ p0,
                                                          int* __restrict__ base0, int* __restrict__ cur0,
                                                          const int* __restrict__ deg1, const int* __restrict__ p1,
                                                          int* __restrict__ base1, int* __restrict__ cur1) {
    __shared__ int s[256];
    int which = blockIdx.x >= NODE_BLOCKS;
    int bb = blockIdx.x - which * NODE_BLOCKS;
    const int* deg = which ? deg1 : deg0;
    const int* partial = which ? p1 : p0;
    int* base = which ? base1 : base0;
    int* cur  = which ? cur1 : cur0;
    int i = bb * 256 + threadIdx.x;
    int t = threadIdx.x;
    int v = (i < N_NODES) ? deg[i] : 0;
    s[t] = v;
    __syncthreads();
    for (int off = 1; off < 256; off <<= 1) {
        int a = (t >= off) ? s[t - off] : 0;
        __syncthreads();
        s[t] += a;
        __syncthreads();
    }
    int excl = s[t] - v + partial[bb];
    if (i < N_NODES) { base[i] = excl; cur[i] = excl; }
}

// scatter packed 4B edges (u16 src | bf16 w) — halves the random-write payload
__global__ __launch_bounds__(256) void scatter2_kernel(const int* __restrict__ es0, const int* __restrict__ ed0,
                                                       const float* __restrict__ ew0, int* __restrict__ cur0,
                                                       int* __restrict__ edge0,
                                                       const int* __restrict__ es1, const int* __restrict__ ed1,
                                                       const float* __restrict__ ew1, int* __restrict__ cur1,
                                                       int* __restrict__ edge1) {
    int b = blockIdx.x;
    if (b < EDGE_BLOCKS) {
        int e = b * 256 + threadIdx.x;
        int p = atomicAdd(&cur0[ed0[e]], 1);
        edge0[p] = pack_edge(es0[e], ew0[e]);
    } else {
        int e = (b - EDGE_BLOCKS) * 256 + threadIdx.x;
        int p = atomicAdd(&cur1[ed1[e]], 1);
        edge1[p] = pack_edge(es1[e], ew1[e]);
    }
}

// ---------------- SpMM1 pull (bf16, d=256): wave per node, 2 edge slots --------------
// slot=lane>>5 walks edges stride-2; 32 lanes x short8 (16B) cover the 512B row.
// Slots combined by shfl_xor(32). 1-ahead prefetch per slot. Edges packed 4B.
__global__ __launch_bounds__(256) void spmm1_pull_kernel(const int* __restrict__ base,
                                                         const int* __restrict__ deg,
                                                         const int* __restrict__ edge_s,
                                                         const short* __restrict__ h0b,
                                                         float* __restrict__ agg0) {
    const int node = blockIdx.x * 4 + (threadIdx.x >> 6);
    const int lane = threadIdx.x & 63;
    const int slot = lane >> 5;
    const int c    = lane & 31;         // feature group: feats c*8..c*8+7
    const int start = base[node];
    const int len   = deg[node];

    float acc[8] = {0.f,0.f,0.f,0.f,0.f,0.f,0.f,0.f};
    int j = slot;
    int e = 0;
    short8 hv = {0,0,0,0,0,0,0,0};
    if (j < len) {
        e  = edge_s[start + j];
        hv = *(const short8*)(h0b + (size_t)(e & 0xFFFF) * NHID + c * 8);
    }
    while (j < len) {
        float wt = bf2f((short)((unsigned)e >> 16));
        int jn = j + 2;
        int en = e; short8 hn = hv;
        if (jn < len) {
            en = edge_s[start + jn];
            hn = *(const short8*)(h0b + (size_t)(en & 0xFFFF) * NHID + c * 8);
        }
        #pragma unroll
        for (int k = 0; k < 8; ++k) acc[k] += wt * bf2f(hv[k]);
        e = en; hv = hn; j = jn;
    }
    #pragma unroll
    for (int k = 0; k < 8; ++k) acc[k] += __shfl_xor(acc[k], 32);
    if (slot == 0) {
        float4 o0 = {acc[0], acc[1], acc[2], acc[3]};
        float4 o1 = {acc[4], acc[5], acc[6], acc[7]};
        float* p = agg0 + (size_t)node * NHID + c * 8;
        *(float4*)p = o0;
        *(float4*)(p + 4) = o1;
    }
}

// ---------------- GEMM2 (MFMA): h2 = relu(agg0 + b1) @ W2, bf16 row-major out --------
__global__ __launch_bounds__(256) void gemm2_mfma_kernel(const float* __restrict__ agg0,
                                                         const float* __restrict__ b1,
                                                         const short* __restrict__ W2t,
                                                         short* __restrict__ h2b) {
    __shared__ short Bs[64 * 264];   // 33 KB, [n][k] pad +8
    __shared__ short As[64 * 32];    // 4 KB
    const int tid  = threadIdx.x;
    const int wave = tid >> 6, lane = tid & 63;
    const int mlo  = lane & 15, q = lane >> 4;
    const int m0   = blockIdx.x * 64;

    {   // stage full W2t [64x256] once
        int n = tid >> 2, seg = (tid & 3) * 64;
        #pragma unroll
        for (int i = 0; i < 8; ++i)
            *(short8*)&Bs[n * 264 + seg + i * 8] =
                *(const short8*)(W2t + n * NHID + seg + i * 8);
    }

    const int ar  = tid >> 2;
    const int acg = (tid & 3) * 8;
    int arow = m0 + ar; if (arow >= N_NODES) arow = N_NODES - 1;
    const float* aptr = agg0 + (size_t)arow * NHID + acg;

    floatx4 acc[4] = {};   // [ntile]

    for (int kc = 0; kc < NHID; kc += 32) {
        float4 a0 = *(const float4*)(aptr + kc);
        float4 a1 = *(const float4*)(aptr + kc + 4);
        float4 c0 = *(const float4*)(b1 + kc + acg);
        float4 c1 = *(const float4*)(b1 + kc + acg + 4);
        float v0 = a0.x + c0.x, v1 = a0.y + c0.y, v2 = a0.z + c0.z, v3 = a0.w + c0.w;
        float v4 = a1.x + c1.x, v5 = a1.y + c1.y, v6 = a1.z + c1.z, v7 = a1.w + c1.w;
        short8 apk;
        apk[0] = f2bf(v0 > 0.f ? v0 : 0.f); apk[1] = f2bf(v1 > 0.f ? v1 : 0.f);
        apk[2] = f2bf(v2 > 0.f ? v2 : 0.f); apk[3] = f2bf(v3 > 0.f ? v3 : 0.f);
        apk[4] = f2bf(v4 > 0.f ? v4 : 0.f); apk[5] = f2bf(v5 > 0.f ? v5 : 0.f);
        apk[6] = f2bf(v6 > 0.f ? v6 : 0.f); apk[7] = f2bf(v7 > 0.f ? v7 : 0.f);
        *(short8*)&As[ar * 32 + acg] = apk;
        __syncthreads();

        short8 af = *(const short8*)&As[(wave * 16 + mlo) * 32 + q * 8];
        #pragma unroll
        for (int u = 0; u < 4; ++u) {
            short8 bfr = *(const short8*)&Bs[(u * 16 + mlo) * 264 + kc + q * 8];
            acc[u] = __builtin_amdgcn_mfma_f32_16x16x32_bf16(af, bfr, acc[u], 0, 0, 0);
        }
        __syncthreads();
    }

    #pragma unroll
    for (int r = 0; r < 4; ++r) {
        int row = m0 + wave * 16 + q * 4 + r;
        if (row < N_NODES) {
            #pragma unroll
            for (int u = 0; u < 4; ++u)
                h2b[(size_t)row * NCLASS + u * 16 + mlo] = f2bf(acc[u][r]);
        }
    }
}

// ---------------- Fused SpMM2 + bias + log_softmax (d=64) ----------------
// Wave per node. slot=lane>>3 (8 slots, 8 edges in flight); f=lane&7 covers feats
// f*8..f*8+7 via short8 (16B). Butterfly slot-reduce => every lane holds its f-group's
// aggregated values; then in-register bias + log_softmax; slot 0 stores.
__global__ __launch_bounds__(256) void spmm2_lsm_kernel(const int* __restrict__ base,
                                                        const int* __restrict__ deg,
                                                        const int* __restrict__ edge_s,
                                                        const short* __restrict__ h2b,
                                                        const float* __restrict__ b2,
                                                        float* __restrict__ out) {
    const int node = blockIdx.x * 4 + (threadIdx.x >> 6);
    const int lane = threadIdx.x & 63;
    const int slot = lane >> 3;
    const int f    = lane & 7;          // feats f*8..f*8+7
    const int start = base[node];
    const int len   = deg[node];

    float acc[8] = {0.f,0.f,0.f,0.f,0.f,0.f,0.f,0.f};
    int j = slot;
    int e = 0;
    short8 hv = {0,0,0,0,0,0,0,0};
    if (j < len) {
        e  = edge_s[start + j];
        hv = *(const short8*)(h2b + (size_t)(e & 0xFFFF) * NCLASS + f * 8);
    }
    while (j < len) {
        float wt = bf2f((short)((unsigned)e >> 16));
        int jn = j + 8;
        int en = e; short8 hn = hv;
        if (jn < len) {
            en = edge_s[start + jn];
            hn = *(const short8*)(h2b + (size_t)(en & 0xFFFF) * NCLASS + f * 8);
        }
        #pragma unroll
        for (int k = 0; k < 8; ++k) acc[k] += wt * bf2f(hv[k]);
        e = en; hv = hn; j = jn;
    }
    // butterfly across slots (lane bits 3,4,5) -> allreduce within f-group
    #pragma unroll
    for (int k = 0; k < 8; ++k) {
        acc[k] += __shfl_xor(acc[k], 8);
        acc[k] += __shfl_xor(acc[k], 16);
        acc[k] += __shfl_xor(acc[k], 32);
    }
    // + bias
    float4 c0 = *(const float4*)(b2 + f * 8);
    float4 c1 = *(const float4*)(b2 + f * 8 + 4);
    float v[8];
    v[0] = acc[0] + c0.x; v[1] = acc[1] + c0.y; v[2] = acc[2] + c0.z; v[3] = acc[3] + c0.w;
    v[4] = acc[4] + c1.x; v[5] = acc[5] + c1.y; v[6] = acc[6] + c1.z; v[7] = acc[7] + c1.w;
    // log_softmax across 64 classes: local 8 + butterfly over f bits (1,2,4)
    float m = v[0];
    #pragma unroll
    for (int k = 1; k < 8; ++k) m = fmaxf(m, v[k]);
    m = fmaxf(m, __shfl_xor(m, 1));
    m = fmaxf(m, __shfl_xor(m, 2));
    m = fmaxf(m, __shfl_xor(m, 4));
    float s = 0.f;
    #pragma unroll
    for (int k = 0; k < 8; ++k) s += __expf(v[k] - m);
    s += __shfl_xor(s, 1);
    s += __shfl_xor(s, 2);
    s += __shfl_xor(s, 4);
    float ls = m + __logf(s);
    if (slot == 0) {
        float4 o0 = {v[0] - ls, v[1] - ls, v[2] - ls, v[3] - ls};
        float4 o1 = {v[4] - ls, v[5] - ls, v[6] - ls, v[7] - ls};
        float* p = out + (size_t)node * NCLASS + f * 8;
        *(float4*)p = o0;
        *(float4*)(p + 4) = o1;
    }
}

extern "C" void kernel_launch(void* const* d_in, const int* in_sizes, int n_in,
                              void* d_out, int out_size, void* d_ws, size_t ws_size,
                              hipStream_t stream) {
    const float* x   = (const float*)d_in[0];
    const int*   es0 = (const int*)  d_in[1];
    const int*   ed0 = (const int*)  d_in[2];
    const float* ew0 = (const float*)d_in[3];
    const int*   es1 = (const int*)  d_in[4];
    const int*   ed1 = (const int*)  d_in[5];
    const float* ew1 = (const float*)d_in[6];
    const float* W1  = (const float*)d_in[7];
    const float* b1  = (const float*)d_in[8];
    const float* W2  = (const float*)d_in[9];
    const float* b2  = (const float*)d_in[10];
    float* out = (float*)d_out;

    // ws layout (102.4 MB):
    //   [0, 25.6MB):   h0b bf16 [50000x256]; later h2b bf16 [50000x64] at [0,6.4)
    //   [25.6,32.6MB): CSR1 (deg1/base1/cursor1/partial1/edge1 packed 4B)
    //   [51.2,102.4):  agg0 fp32 [50000x256]
    char* ws = (char*)d_ws;
    const size_t SZ_H0 = (size_t)N_NODES * NHID * sizeof(short);   // 25.6 MB
    short* h0b  = (short*)ws;
    short* h2b  = (short*)ws;
    float* agg0 = (float*)(ws + (size_t)N_NODES * NHID * sizeof(float));   // 51.2MB

    char* c1 = ws + SZ_H0;
    int*   deg1     = (int*)c1;
    int*   base1    = deg1 + N_NODES;
    int*   cursor1  = base1 + N_NODES;
    int*   partial1 = cursor1 + N_NODES;
    int*   edge1    = partial1 + 1024;

    // d_out scratch (12.8 MB; CSR0 dead after spmm1; Wt/W2t dead after gemms;
    // final fused spmm2+logsoftmax overwrites all of d_out):
    int*   deg0     = (int*)d_out;
    int*   base0    = deg0 + N_NODES;
    int*   cursor0  = base0 + N_NODES;
    int*   partial0 = cursor0 + N_NODES;
    int*   edge0    = partial0 + 1024;
    short* Wt       = (short*)((char*)d_out + (8u << 20));
    short* W2t      = (short*)((char*)d_out + (9u << 20));

    // ---- build both CSRs up-front (fused) ----
    hipMemsetAsync(deg0, 0, N_NODES * sizeof(int), stream);
    hipMemsetAsync(deg1, 0, N_NODES * sizeof(int), stream);
    hist2_kernel<<<2 * EDGE_BLOCKS, 256, 0, stream>>>(ed0, deg0, ed1, deg1);
    scan_partial2_kernel<<<2 * NODE_BLOCKS, 256, 0, stream>>>(deg0, partial0, deg1, partial1);
    scan_top2_kernel<<<2, 256, 0, stream>>>(partial0, partial1);
    scan_final2_kernel<<<2 * NODE_BLOCKS, 256, 0, stream>>>(deg0, partial0, base0, cursor0,
                                                            deg1, partial1, base1, cursor1);
    scatter2_kernel<<<2 * EDGE_BLOCKS, 256, 0, stream>>>(es0, ed0, ew0, cursor0, edge0,
                                                         es1, ed1, ew1, cursor1, edge1);

    // ---- weights ----
    cast_w1t_kernel<<<NFEAT, 256, 0, stream>>>(W1, Wt);
    cast_w2t_kernel<<<NCLASS, 256, 0, stream>>>(W2, W2t);

    // ---- layer 1 ----
    gemm1_mfma_kernel<<<MTILES, 256, 0, stream>>>(x, Wt, h0b);
    spmm1_pull_kernel<<<N_NODES / 4, 256, 0, stream>>>(base0, deg0, edge0, h0b, agg0);

    // ---- layer 2 (spmm2 fused with bias + log_softmax, writes out directly) ----
    gemm2_mfma_kernel<<<MTILES, 256, 0, stream>>>(agg0, b1, W2t, h2b);
    spmm2_lsm_kernel<<<N_NODES / 4, 256, 0, stream>>>(base1, deg1, edge1, h2b, b2, out);
}